// Round 12
// baseline (518.305 us; speedup 1.0000x reference)
//
#include <hip/hip_runtime.h>

#define EPS_BN 1e-4f

typedef _Float16 f16x8 __attribute__((ext_vector_type(8)));
typedef float f32x4 __attribute__((ext_vector_type(4)));

// ---------------------------------------------------------------------------
// bn_relu -> fp16 (standalone; only for the first layer input)
// ---------------------------------------------------------------------------
template <int C>
__global__ __launch_bounds__(256) void bn_relu_kernel(
    const float* __restrict__ x, const float* __restrict__ bn,
    _Float16* __restrict__ out, int n_const, const int* __restrict__ n_dev)
{
    const int n = n_dev ? *n_dev : n_const;
    const long total = (long)n * C;
    const long i = (long)blockIdx.x * blockDim.x + threadIdx.x;
    if (i >= total) return;
    const int c = (int)(i & (C - 1));
    const float g = bn[c], b = bn[C + c], m = bn[2 * C + c], v = bn[3 * C + c];
    const float val = (x[i] - m) * (g * rsqrtf(v + EPS_BN)) + b;
    out[i] = (_Float16)fmaxf(val, 0.f);
}

// ---------------------------------------------------------------------------
// Build row-major gather table: Trow[pout[k,p]*KPAD + k] = pin[k,p]
// ---------------------------------------------------------------------------
__global__ __launch_bounds__(256) void build_table_kernel(
    const int* __restrict__ pin, const int* __restrict__ pout,
    int K, int P, int pad_const, const int* __restrict__ pad_dev,
    int KPAD, int* __restrict__ T)
{
    const int e = blockIdx.x * 256 + threadIdx.x;
    if (e >= K * P) return;
    const int pad = pad_dev ? *pad_dev : pad_const;
    const int in = pin[e];
    if (in == pad) return;
    const int k = e / P;
    T[(size_t)pout[e] * KPAD + k] = in;
}

// ---------------------------------------------------------------------------
// Merged weight convert+transpose: 7 segments, blockIdx.y selects segment.
// src [K][CI][CO] fp32 -> dst [K][CO][CI] fp16
// ---------------------------------------------------------------------------
struct WSeg { const float* src; _Float16* dst; int tot, ci, co; };
struct WAll { WSeg s[7]; };

__global__ __launch_bounds__(256) void wcvt_all_kernel(WAll w)
{
    const WSeg sg = w.s[blockIdx.y];
    const int per = sg.ci * sg.co;
    for (int e = blockIdx.x * 256 + threadIdx.x; e < sg.tot; e += gridDim.x * 256) {
        const int k = e / per, r = e % per;
        const int ci = r / sg.co, co = r % sg.co;
        sg.dst[(size_t)k * per + (size_t)co * sg.ci + ci] = (_Float16)sg.src[e];
    }
}

// ---------------------------------------------------------------------------
// MFMA gather conv, shared-A, TG taps/phase, COUNTED-WAIT PIPELINE:
//  - raw s_barrier + per-thread lgkmcnt(0) only (NO vmcnt drain at barriers;
//    __syncthreads would drain all in-flight gathers every phase = the stall)
//  - A gathers prefetched DEPTH-2 (issue p+2 at phase p; two reg sets,
//    parity-static via full unroll)
//  - B (weights) single reg set, re-loaded for p+1 right after MFMA(p)
// Block = 256 thr = 4 waves = WR row-groups x WC cout-groups; tile BM rows.
// LINEAR-SLOT staging (conflict-free; LDS slot == frag linear index):
//   q=f>>6; kk=q%KK; r=(q/KK)*16+(f&15); seg=kk*4+((f>>4)&3)
// Read slot: a16 = tg*SLOTS + ((wr*M_REP+m)*KK + kk)*64 + lane
// C/D: col = lane&15, row = (lane>>4)*4 + reg   [m89]
// ---------------------------------------------------------------------------
template <int CIN, int COUT, int K, int KPAD, int WR, int WC, int M_REP,
          int TG, int MINW>
__global__ __launch_bounds__(256, MINW) void mconv_kernel(
    const _Float16* __restrict__ x, const _Float16* __restrict__ Wt,
    const int* __restrict__ Trow,
    const float* __restrict__ add, float* __restrict__ fout,
    const float* __restrict__ bnx, _Float16* __restrict__ hout,
    int n_const, const int* __restrict__ n_dev)
{
    static_assert(K % TG == 0, "K must be divisible by TG");
    static_assert(WR * WC == 4, "4 waves");
    static_assert(WC * 16 == COUT, "wave covers one 16-cout slice");
    constexpr int BM = WR * M_REP * 16;
    constexpr int KK = CIN / 32;
    constexpr int SEGS = CIN / 8;
    constexpr int SLOTS = BM * SEGS;          // 16B slots per tap tile
    constexpr int SPT = (SLOTS + 255) / 256;  // slots per thread
    constexpr int NP = K / TG;
    __shared__ _Float16 A[2][TG * SLOTS * 8];
    __shared__ int TL[BM * K];

    const int n = n_dev ? *n_dev : n_const;
    const int row0 = blockIdx.x * BM;
    if (row0 >= n) return;                    // block-uniform exit

    const int tid = threadIdx.x;
    const int wave = tid >> 6, lane = tid & 63;
    const int lrow = lane & 15, g = lane >> 4;
    const int wr = wave / WC, wc = wave % WC;

    for (int idx = tid; idx < BM * K; idx += 256) {
        const int r = idx / K, k = idx % K;
        TL[idx] = (row0 + r < n) ? Trow[(size_t)(row0 + r) * KPAD + k] : -1;
    }
    __syncthreads();   // once, before pipeline; full drain OK here

    auto stage_issue = [&](int p, f16x8 (&v)[TG][SPT]) {
#pragma unroll
        for (int s = 0; s < SPT; ++s) {
            const int f = tid + s * 256;
            if (f < SLOTS) {
                const int q = f >> 6;
                const int kk = q % KK;
                const int r = (q / KK) * 16 + (f & 15);
                const int seg = kk * 4 + ((f >> 4) & 3);
#pragma unroll
                for (int tg = 0; tg < TG; ++tg) {
                    const int t = TL[r * K + (p * TG + tg)];
                    v[tg][s] = (t >= 0)
                        ? *(const f16x8*)(x + (size_t)t * CIN + seg * 8)
                        : (f16x8)(_Float16)0.f;
                }
            }
        }
    };
    auto stage_write = [&](int buf, f16x8 (&v)[TG][SPT]) {
#pragma unroll
        for (int s = 0; s < SPT; ++s) {
            const int f = tid + s * 256;
            if (f < SLOTS) {
#pragma unroll
                for (int tg = 0; tg < TG; ++tg)
                    *(f16x8*)(&A[buf][(tg * SLOTS + f) * 8]) = v[tg][s];
            }
        }
    };
    auto bload = [&](int p, f16x8 (&b)[TG][KK]) {
#pragma unroll
        for (int tg = 0; tg < TG; ++tg) {
            const int tap = p * TG + tg;
            const _Float16* wb = Wt + ((size_t)tap * COUT + wc * 16 + lrow) * CIN
                               + g * 8;
#pragma unroll
            for (int kk = 0; kk < KK; ++kk)
                b[tg][kk] = *(const f16x8*)(wb + kk * 32);
        }
    };

    f32x4 acc[M_REP];
#pragma unroll
    for (int m = 0; m < M_REP; ++m) acc[m] = (f32x4)0.f;

    f16x8 sA0[TG][SPT], sA1[TG][SPT];
    f16x8 sB[TG][KK];

    // ---- prologue: A(0), A(1) in flight; B(0) blocking; write A(0) ----
    stage_issue(0, sA0);
    if (NP > 1) stage_issue(1, sA1);
    bload(0, sB);
    stage_write(0, sA0);
    asm volatile("s_waitcnt lgkmcnt(0)" ::: "memory");
    __builtin_amdgcn_sched_barrier(0);
    __builtin_amdgcn_s_barrier();
    __builtin_amdgcn_sched_barrier(0);

#pragma unroll
    for (int p = 0; p < NP; ++p) {
        // issue A for p+2 into set[p&1] (that set's data was LDS-written at p-1)
        if (p + 2 < NP) {
            if (p & 1) stage_issue(p + 2, sA1);
            else       stage_issue(p + 2, sA0);
        }

        // MFMA on A[p&1] with current B
        const _Float16* Ab = A[p & 1];
        __builtin_amdgcn_s_setprio(1);
#pragma unroll
        for (int tg = 0; tg < TG; ++tg)
#pragma unroll
            for (int m = 0; m < M_REP; ++m)
#pragma unroll
                for (int kk = 0; kk < KK; ++kk) {
                    const int a16 = tg * SLOTS + ((wr * M_REP + m) * KK + kk) * 64
                                  + lane;
                    const f16x8 av = *(const f16x8*)(&Ab[a16 * 8]);
                    acc[m] = __builtin_amdgcn_mfma_f32_16x16x32_f16(
                        av, sB[tg][kk], acc[m], 0, 0, 0);
                }
        __builtin_amdgcn_s_setprio(0);

        // reload B for p+1 (flies over barrier; WAR on regs just consumed)
        if (p + 1 < NP) bload(p + 1, sB);

        // write A(p+1) from set[(p+1)&1] (issued at p-1; ~2 phases in flight)
        if (p + 1 < NP) {
            if (p & 1) stage_write((p + 1) & 1, sA0);
            else       stage_write((p + 1) & 1, sA1);
            asm volatile("s_waitcnt lgkmcnt(0)" ::: "memory");
            __builtin_amdgcn_sched_barrier(0);
            __builtin_amdgcn_s_barrier();
            __builtin_amdgcn_sched_barrier(0);
        }
    }

    // ---- epilogue: add, fp32 out, fused bn_relu fp16 out ----
#pragma unroll
    for (int m = 0; m < M_REP; ++m) {
        const int rbase = row0 + (wr * M_REP + m) * 16 + g * 4;
        const int c = wc * 16 + lrow;
        float sc = 0.f, mm = 0.f, be = 0.f;
        if (hout) {
            const float ga = bnx[c], va = bnx[3 * COUT + c];
            be = bnx[COUT + c];
            mm = bnx[2 * COUT + c];
            sc = ga * rsqrtf(va + EPS_BN);
        }
#pragma unroll
        for (int i = 0; i < 4; ++i) {
            const int r = rbase + i;
            if (r < n) {
                const size_t o = (size_t)r * COUT + c;
                float v = acc[m][i];
                if (add) v += add[o];
                if (fout) fout[o] = v;
                if (hout) hout[o] = (_Float16)fmaxf((v - mm) * sc + be, 0.f);
            }
        }
    }
}

// ---------------------------------------------------------------------------
// concat + fused bn_relu: fout[i] = concat(a,b); hout[i] = bn_relu(fout[i])
// ---------------------------------------------------------------------------
__global__ __launch_bounds__(256) void concat_bn_kernel(
    const float* __restrict__ a, const float* __restrict__ b,
    float* __restrict__ fout, const float* __restrict__ bnx,
    _Float16* __restrict__ hout, int n)
{
    const int i = blockIdx.x * 256 + threadIdx.x;
    if (i >= n * 64) return;
    const int row = i >> 6, c = i & 63;
    const float v = (c < 32) ? a[row * 32 + c] : b[row * 32 + (c - 32)];
    fout[i] = v;
    const float g = bnx[c], be = bnx[64 + c], m = bnx[128 + c], va = bnx[192 + c];
    hout[i] = (_Float16)fmaxf((v - m) * (g * rsqrtf(va + EPS_BN)) + be, 0.f);
}

// ---------------------------------------------------------------------------
// dense matmul: out[n x 32] = x[n x 64] @ W[64 x 32]   (fp32 scalar)
// ---------------------------------------------------------------------------
__global__ __launch_bounds__(256) void dense_mm_kernel(
    const float* __restrict__ x, const float* __restrict__ W,
    float* __restrict__ out, int n)
{
    __shared__ float Wl[64 * 32];
    for (int i = threadIdx.x; i < 64 * 32; i += 256) Wl[i] = W[i];
    __syncthreads();
    const int idx = blockIdx.x * 256 + threadIdx.x;
    const int row = idx >> 5, c = idx & 31;
    if (row >= n) return;
    const float* xr = x + (size_t)row * 64;
    float acc = 0.f;
#pragma unroll
    for (int q = 0; q < 16; ++q) {
        const float4 xv = *(const float4*)(xr + 4 * q);
        acc = fmaf(xv.x, Wl[(4 * q + 0) * 32 + c], acc);
        acc = fmaf(xv.y, Wl[(4 * q + 1) * 32 + c], acc);
        acc = fmaf(xv.z, Wl[(4 * q + 2) * 32 + c], acc);
        acc = fmaf(xv.w, Wl[(4 * q + 3) * 32 + c], acc);
    }
    out[(size_t)row * 32 + c] = acc;
}

// ---------------------------------------------------------------------------

extern "C" void kernel_launch(void* const* d_in, const int* in_sizes, int n_in,
                              void* d_out, int out_size, void* d_ws, size_t ws_size,
                              hipStream_t stream)
{
    const float* feats   = (const float*)d_in[0];
    const float* res0_W  = (const float*)d_in[1];   // (2,2,27,32,32)
    const float* res0_bn = (const float*)d_in[2];   // (2,2,4,32)
    const float* down_bn = (const float*)d_in[3];   // (4,32)
    const float* down_W  = (const float*)d_in[4];   // (8,32,64)
    const float* res1_W  = (const float*)d_in[5];   // (2,2,27,64,64)
    const float* res1_bn = (const float*)d_in[6];   // (2,2,4,64)
    const float* up_bn   = (const float*)d_in[7];   // (4,64)
    const float* up_W    = (const float*)d_in[8];   // (8,64,32)
    const float* t0_bn1  = (const float*)d_in[9];   // (4,64)
    const float* t0_W1   = (const float*)d_in[10];  // (27,64,32)
    const float* t0_bn2  = (const float*)d_in[11];  // (4,32)
    const float* t0_W2   = (const float*)d_in[12];  // (27,32,32)
    const float* t0_Wsc  = (const float*)d_in[13];  // (64,32)
    const float* t1_W    = (const float*)d_in[14];  // (2,27,32,32)
    const float* t1_bn   = (const float*)d_in[15];  // (2,4,32)
    const int* s0i = (const int*)d_in[16];
    const int* s0o = (const int*)d_in[17];
    const int* s1i = (const int*)d_in[18];
    const int* s1o = (const int*)d_in[19];
    const int* dni = (const int*)d_in[20];
    const int* dno = (const int*)d_in[21];
    const int* n1p = (const int*)d_in[22];          // device scalar n1

    const int n0 = in_sizes[0] / 32;
    const int P0 = in_sizes[16] / 27;
    const int P1 = in_sizes[18] / 27;
    const int Pd = in_sizes[20] / 8;

    // ---- workspace layout (all chunks 16B-aligned) ----
    const size_t bufN = (size_t)n0 * 64;
    float* F1 = (float*)d_ws;
    float* F2 = F1 + bufN;
    float* F3 = F2 + bufN;
    float* F4 = F3 + bufN;
    _Float16* Ha = (_Float16*)(F4 + bufN);           // fp16 ping
    _Float16* Hb = Ha + bufN;                        // pong
    int* T0r = (int*)(Hb + bufN);                    // [n0][28]
    int* T1r = T0r + (size_t)n0 * 28;                // [n0][28]
    int* Tdr = T1r + (size_t)n0 * 28;                // [n0][8]
    int* Tur = Tdr + (size_t)n0 * 8;                 // [n0][8]
    _Float16* Wt_res0 = (_Float16*)(Tur + (size_t)n0 * 8);  // 108*1024
    _Float16* Wt_down = Wt_res0 + 108 * 1024;        // 8*2048
    _Float16* Wt_res1 = Wt_down + 8 * 2048;          // 108*4096
    _Float16* Wt_up   = Wt_res1 + (size_t)108 * 4096;// 8*2048
    _Float16* Wt_t01  = Wt_up + 8 * 2048;            // 27*2048
    _Float16* Wt_t02  = Wt_t01 + 27 * 2048;          // 27*1024
    _Float16* Wt_t1   = Wt_t02 + 27 * 1024;          // 54*1024

    // ---- gather tables (single memset over contiguous T region) ----
    hipMemsetAsync(T0r, 0xFF, (size_t)n0 * 72 * 4, stream);
    auto build = [&](const int* pin, const int* pout, int K, int P,
                     int padc, const int* padd, int KPAD, int* T) {
        hipLaunchKernelGGL(build_table_kernel, dim3((K * P + 255) / 256),
                           dim3(256), 0, stream, pin, pout, K, P, padc, padd,
                           KPAD, T);
    };
    build(s0i, s0o, 27, P0, n0, nullptr, 28, T0r);
    build(s1i, s1o, 27, P1, 0, n1p, 28, T1r);
    build(dni, dno, 8, Pd, n0, nullptr, 8, Tdr);
    build(dno, dni, 8, Pd, 0, n1p, 8, Tur);   // up: roles swapped

    // ---- merged weight convert+transpose (1 launch) ----
    WAll wa;
    wa.s[0] = {res0_W, Wt_res0, 108 * 1024, 32, 32};
    wa.s[1] = {down_W, Wt_down, 8 * 2048, 32, 64};
    wa.s[2] = {res1_W, Wt_res1, 108 * 4096, 64, 64};
    wa.s[3] = {up_W,   Wt_up,   8 * 2048, 64, 32};
    wa.s[4] = {t0_W1,  Wt_t01,  27 * 2048, 64, 32};
    wa.s[5] = {t0_W2,  Wt_t02,  27 * 1024, 32, 32};
    wa.s[6] = {t1_W,   Wt_t1,   54 * 1024, 32, 32};
    hipLaunchKernelGGL(wcvt_all_kernel, dim3((108 * 4096 + 255) / 256, 7),
                       dim3(256), 0, stream, wa);

    const int g32 = (n0 * 32 + 255) / 256;
    const int g64 = (n0 * 64 + 255) / 256;
    const int gm64 = (n0 + 63) / 64;   // BM=64 grids
    const int gm32 = (n0 + 31) / 32;   // BM=32 grids (level-1: early exit)

    // 32->32 K=27: BM=64 (WR=2,WC=2,M_REP=2), TG=3
    auto mc3232 = [&](const _Float16* xin, const _Float16* Wtp, const int* T,
                      const float* add, float* fo, const float* bn, _Float16* ho,
                      int nc, const int* nd) {
        hipLaunchKernelGGL((mconv_kernel<32, 32, 27, 28, 2, 2, 2, 3, 4>),
                           dim3(gm64), dim3(256), 0, stream,
                           xin, Wtp, T, add, fo, bn, ho, nc, nd);
    };
    // 64->64 K=27: BM=32 (WR=1,WC=4,M_REP=2), TG=3
    auto mc6464 = [&](const _Float16* xin, const _Float16* Wtp,
                      const float* add, float* fo, const float* bn, _Float16* ho) {
        hipLaunchKernelGGL((mconv_kernel<64, 64, 27, 28, 1, 4, 2, 3, 4>),
                           dim3(gm32), dim3(256), 0, stream,
                           xin, Wtp, T1r, add, fo, bn, ho, 0, n1p);
    };

    // 0: first bn_relu (feats -> Ha)
    hipLaunchKernelGGL((bn_relu_kernel<32>), dim3(g32), dim3(256), 0, stream,
                       feats, res0_bn + 0 * 128, Ha, n0, nullptr);
    // 1: res0.0 conv0: Ha -> Hb
    mc3232(Ha, Wt_res0 + 0 * 27 * 1024, T0r, nullptr, nullptr,
           res0_bn + 1 * 128, Hb, n0, nullptr);
    // 2: res0.0 conv1 (+feats): Hb -> F2, Ha
    mc3232(Hb, Wt_res0 + 1 * 27 * 1024, T0r, feats, F2,
           res0_bn + 2 * 128, Ha, n0, nullptr);
    // 3: res0.1 conv0: Ha -> Hb
    mc3232(Ha, Wt_res0 + 2 * 27 * 1024, T0r, nullptr, nullptr,
           res0_bn + 3 * 128, Hb, n0, nullptr);
    // 4: res0.1 conv1 (+F2): Hb -> F3 (identity), Ha [bn=down_bn]
    mc3232(Hb, Wt_res0 + 3 * 27 * 1024, T0r, F2, F3, down_bn, Ha, n0, nullptr);
    // 5: down conv (32->64, K=8, BM=32, TG=2): Ha -> F1 (n1 x 64), Hb
    hipLaunchKernelGGL((mconv_kernel<32, 64, 8, 8, 1, 4, 2, 2, 4>),
                       dim3(gm32), dim3(256), 0, stream, Ha, Wt_down, Tdr,
                       (const float*)nullptr, F1, res1_bn + 0 * 256, Hb, 0, n1p);
    // 6: res1.0 conv0: Hb -> Ha
    mc6464(Hb, Wt_res1 + 0 * 27 * 4096, nullptr, nullptr, res1_bn + 1 * 256, Ha);
    // 7: res1.0 conv1 (+F1): Ha -> F4, Hb
    mc6464(Ha, Wt_res1 + 1 * 27 * 4096, F1, F4, res1_bn + 2 * 256, Hb);
    // 8: res1.1 conv0: Hb -> Ha
    mc6464(Hb, Wt_res1 + 2 * 27 * 4096, nullptr, nullptr, res1_bn + 3 * 256, Ha);
    // 9: res1.1 conv1 (+F4): Ha -> F1, Hb [bn=up_bn]
    mc6464(Ha, Wt_res1 + 3 * 27 * 4096, F4, F1, up_bn, Hb);
    // 10: up conv (64->32, K=8, BM=32, TG=2): Hb(level1) -> F2 (n0 x 32)
    hipLaunchKernelGGL((mconv_kernel<64, 32, 8, 8, 2, 2, 1, 2, 4>),
                       dim3(gm32), dim3(256), 0, stream, Hb, Wt_up, Tur,
                       (const float*)nullptr, F2, (const float*)nullptr,
                       (_Float16*)nullptr, n0, nullptr);
    // 11: concat+bn: [F3|F2] -> F4 fp32, Ha fp16 [bn=t0_bn1]
    hipLaunchKernelGGL(concat_bn_kernel, dim3(g64), dim3(256), 0, stream,
                       F3, F2, F4, t0_bn1, Ha, n0);
    // 12: tail0 conv1 (64->32, K=27, BM=32, TG=3): Ha -> Hb [bn=t0_bn2]
    hipLaunchKernelGGL((mconv_kernel<64, 32, 27, 28, 2, 2, 1, 3, 4>),
                       dim3(gm32), dim3(256), 0, stream, Ha, Wt_t01, T0r,
                       (const float*)nullptr, (float*)nullptr, t0_bn2, Hb,
                       n0, nullptr);
    // 13: shortcut: F2 = F4 @ Wsc
    hipLaunchKernelGGL(dense_mm_kernel, dim3(g32), dim3(256), 0, stream,
                       F4, t0_Wsc, F2, n0);
    // 14: tail0 conv2 (+F2): Hb -> F2, Ha [bn=t1_bn0]  (1:1 in-place safe)
    mc3232(Hb, Wt_t02, T0r, F2, F2, t1_bn + 0 * 128, Ha, n0, nullptr);
    // 15: tail1 conv0: Ha -> Hb
    mc3232(Ha, Wt_t1 + 0 * 27 * 1024, T0r, nullptr, nullptr,
           t1_bn + 1 * 128, Hb, n0, nullptr);
    // 16: tail1 conv1 (+F2): Hb -> d_out
    mc3232(Hb, Wt_t1 + 1 * 27 * 1024, T0r, F2, (float*)d_out,
           nullptr, nullptr, n0, nullptr);
}

// Round 13
// 471.139 us; speedup vs baseline: 1.1001x; 1.1001x over previous
//
#include <hip/hip_runtime.h>

#define EPS_BN 1e-4f

typedef _Float16 f16x8 __attribute__((ext_vector_type(8)));
typedef float f32x4 __attribute__((ext_vector_type(4)));

// ---------------------------------------------------------------------------
// bn_relu -> fp16 (standalone; only for the first layer input)
// ---------------------------------------------------------------------------
template <int C>
__global__ __launch_bounds__(256) void bn_relu_kernel(
    const float* __restrict__ x, const float* __restrict__ bn,
    _Float16* __restrict__ out, int n_const, const int* __restrict__ n_dev)
{
    const int n = n_dev ? *n_dev : n_const;
    const long total = (long)n * C;
    const long i = (long)blockIdx.x * blockDim.x + threadIdx.x;
    if (i >= total) return;
    const int c = (int)(i & (C - 1));
    const float g = bn[c], b = bn[C + c], m = bn[2 * C + c], v = bn[3 * C + c];
    const float val = (x[i] - m) * (g * rsqrtf(v + EPS_BN)) + b;
    out[i] = (_Float16)fmaxf(val, 0.f);
}

// ---------------------------------------------------------------------------
// Build row-major gather table: Trow[pout[k,p]*KPAD + k] = pin[k,p]
// ---------------------------------------------------------------------------
__global__ __launch_bounds__(256) void build_table_kernel(
    const int* __restrict__ pin, const int* __restrict__ pout,
    int K, int P, int pad_const, const int* __restrict__ pad_dev,
    int KPAD, int* __restrict__ T)
{
    const int e = blockIdx.x * 256 + threadIdx.x;
    if (e >= K * P) return;
    const int pad = pad_dev ? *pad_dev : pad_const;
    const int in = pin[e];
    if (in == pad) return;
    const int k = e / P;
    T[(size_t)pout[e] * KPAD + k] = in;
}

// ---------------------------------------------------------------------------
// Merged weight convert+transpose: 7 segments, blockIdx.y selects segment.
// src [K][CI][CO] fp32 -> dst [K][CO][CI] fp16
// ---------------------------------------------------------------------------
struct WSeg { const float* src; _Float16* dst; int tot, ci, co; };
struct WAll { WSeg s[7]; };

__global__ __launch_bounds__(256) void wcvt_all_kernel(WAll w)
{
    const WSeg sg = w.s[blockIdx.y];
    const int per = sg.ci * sg.co;
    for (int e = blockIdx.x * 256 + threadIdx.x; e < sg.tot; e += gridDim.x * 256) {
        const int k = e / per, r = e % per;
        const int ci = r / sg.co, co = r % sg.co;
        sg.dst[(size_t)k * per + (size_t)co * sg.ci + ci] = (_Float16)sg.src[e];
    }
}

// ---------------------------------------------------------------------------
// MFMA gather conv. KEY CHANGE (r13): B (weights) staged through LDS too —
// global B was 6x the vmem REQUEST count of A (every lane its own 16B load,
// line-divergent) and TA request-rate is the measured wall. Now per tap:
//   A-tile (BM x CIN) + B-tile (CIN x COUT) each staged once per block with
//   coalesced 16B/thread loads; MFMA reads both operands via ds_read.
// B LDS swizzle (both sides): slot' = slot ^ (cout & 7)   [16B granularity]
// A staging linear-slot (conflict-free, as r11). One tap per phase (TG=1),
// double-buffered, issue-early/write-late, plain __syncthreads.
// Block = 256 thr = 4 waves = WR row-groups x WC cout-groups; tile BM rows.
// A coords from slot f: q=f>>6; kk=q%KK; r=(q/KK)*16+(f&15); seg=kk*4+((f>>4)&3)
// A read slot: ((wr*M_REP+m)*KK + kk)*64 + lane
// C/D: col = lane&15, row = (lane>>4)*4 + reg   [m89]
// ---------------------------------------------------------------------------
template <int CIN, int COUT, int K, int KPAD, int WR, int WC, int M_REP,
          int MINW>
__global__ __launch_bounds__(256, MINW) void mconv_kernel(
    const _Float16* __restrict__ x, const _Float16* __restrict__ Wt,
    const int* __restrict__ Trow,
    const float* __restrict__ add, float* __restrict__ fout,
    const float* __restrict__ bnx, _Float16* __restrict__ hout,
    int n_const, const int* __restrict__ n_dev)
{
    static_assert(WR * WC == 4, "4 waves");
    static_assert(WC * 16 == COUT, "wave covers one 16-cout slice");
    constexpr int BM = WR * M_REP * 16;
    constexpr int KK = CIN / 32;
    constexpr int SLOTS_A = BM * (CIN / 8);       // 16B slots, A tap tile
    constexpr int SLOTS_B = CIN * COUT / 8;       // 16B slots, B tap tile
    constexpr int SPT_B = (SLOTS_B + 255) / 256;
    constexpr int ROWSLOT = CIN / 8;              // B slots per cout row
    static_assert(SLOTS_A <= 256, "one A slot per thread");
    __shared__ _Float16 Abuf[2][SLOTS_A * 8];
    __shared__ _Float16 Bbuf[2][SLOTS_B * 8];
    __shared__ int TL[BM * K];

    const int n = n_dev ? *n_dev : n_const;
    const int row0 = blockIdx.x * BM;
    if (row0 >= n) return;                        // block-uniform exit

    const int tid = threadIdx.x;
    const int wave = tid >> 6, lane = tid & 63;
    const int lrow = lane & 15, g = lane >> 4;
    const int wr = wave / WC, wc = wave % WC;

    for (int idx = tid; idx < BM * K; idx += 256) {
        const int r = idx / K, k = idx % K;
        TL[idx] = (row0 + r < n) ? Trow[(size_t)(row0 + r) * KPAD + k] : -1;
    }
    __syncthreads();

    // A gather coords for this thread's fixed slot
    const int qa   = tid >> 6;
    const int kka  = qa % KK;
    const int ra   = (qa / KK) * 16 + (tid & 15);
    const int sega = kka * 4 + ((tid >> 4) & 3);

    auto issueA = [&](int k, f16x8& v) {
        if (tid < SLOTS_A) {
            const int t = TL[ra * K + k];
            v = (t >= 0) ? *(const f16x8*)(x + (size_t)t * CIN + sega * 8)
                         : (f16x8)(_Float16)0.f;
        }
    };
    auto writeA = [&](int buf, const f16x8& v) {
        if (tid < SLOTS_A) *(f16x8*)(&Abuf[buf][tid * 8]) = v;
    };
    auto issueB = [&](int k, f16x8 (&v)[SPT_B]) {
        const _Float16* wt = Wt + (size_t)k * CIN * COUT;
#pragma unroll
        for (int s = 0; s < SPT_B; ++s) {
            const int fb = tid + s * 256;
            if (fb < SLOTS_B) v[s] = *(const f16x8*)(wt + fb * 8);
        }
    };
    auto writeB = [&](int buf, const f16x8 (&v)[SPT_B]) {
#pragma unroll
        for (int s = 0; s < SPT_B; ++s) {
            const int fb = tid + s * 256;
            if (fb < SLOTS_B) {
                const int cob = fb / ROWSLOT;
                const int sw = fb ^ (cob & 7);    // 16B-slot XOR swizzle
                *(f16x8*)(&Bbuf[buf][sw * 8]) = v[s];
            }
        }
    };

    f32x4 acc[M_REP];
#pragma unroll
    for (int m = 0; m < M_REP; ++m) acc[m] = (f32x4)0.f;

    f16x8 sA;
    f16x8 sB[SPT_B];

    issueA(0, sA);
    issueB(0, sB);
    writeA(0, sA);
    writeB(0, sB);
    __syncthreads();

    const int co = wc * 16 + lrow;               // this lane's B cout row
    for (int p = 0; p < K; ++p) {
        if (p + 1 < K) { issueA(p + 1, sA); issueB(p + 1, sB); }

        const int buf = p & 1;
        f16x8 bv[KK];
#pragma unroll
        for (int kk = 0; kk < KK; ++kk) {
            const int s = co * ROWSLOT + kk * 4 + g;
            const int sw = s ^ (co & 7);
            bv[kk] = *(const f16x8*)(&Bbuf[buf][sw * 8]);
        }
        __builtin_amdgcn_s_setprio(1);
#pragma unroll
        for (int m = 0; m < M_REP; ++m)
#pragma unroll
            for (int kk = 0; kk < KK; ++kk) {
                const int a16 = ((wr * M_REP + m) * KK + kk) * 64 + lane;
                const f16x8 av = *(const f16x8*)(&Abuf[buf][a16 * 8]);
                acc[m] = __builtin_amdgcn_mfma_f32_16x16x32_f16(
                    av, bv[kk], acc[m], 0, 0, 0);
            }
        __builtin_amdgcn_s_setprio(0);

        if (p + 1 < K) { writeA(buf ^ 1, sA); writeB(buf ^ 1, sB); }
        __syncthreads();
    }

    // ---- epilogue: add, fp32 out, fused bn_relu fp16 out ----
#pragma unroll
    for (int m = 0; m < M_REP; ++m) {
        const int rbase = row0 + (wr * M_REP + m) * 16 + g * 4;
        const int c = wc * 16 + lrow;
        float sc = 0.f, mm = 0.f, be = 0.f;
        if (hout) {
            const float ga = bnx[c], va = bnx[3 * COUT + c];
            be = bnx[COUT + c];
            mm = bnx[2 * COUT + c];
            sc = ga * rsqrtf(va + EPS_BN);
        }
#pragma unroll
        for (int i = 0; i < 4; ++i) {
            const int r = rbase + i;
            if (r < n) {
                const size_t o = (size_t)r * COUT + c;
                float v = acc[m][i];
                if (add) v += add[o];
                if (fout) fout[o] = v;
                if (hout) hout[o] = (_Float16)fmaxf((v - mm) * sc + be, 0.f);
            }
        }
    }
}

// ---------------------------------------------------------------------------
// concat + fused bn_relu: fout[i] = concat(a,b); hout[i] = bn_relu(fout[i])
// ---------------------------------------------------------------------------
__global__ __launch_bounds__(256) void concat_bn_kernel(
    const float* __restrict__ a, const float* __restrict__ b,
    float* __restrict__ fout, const float* __restrict__ bnx,
    _Float16* __restrict__ hout, int n)
{
    const int i = blockIdx.x * 256 + threadIdx.x;
    if (i >= n * 64) return;
    const int row = i >> 6, c = i & 63;
    const float v = (c < 32) ? a[row * 32 + c] : b[row * 32 + (c - 32)];
    fout[i] = v;
    const float g = bnx[c], be = bnx[64 + c], m = bnx[128 + c], va = bnx[192 + c];
    hout[i] = (_Float16)fmaxf((v - m) * (g * rsqrtf(va + EPS_BN)) + be, 0.f);
}

// ---------------------------------------------------------------------------
// dense matmul: out[n x 32] = x[n x 64] @ W[64 x 32]   (fp32 scalar)
// ---------------------------------------------------------------------------
__global__ __launch_bounds__(256) void dense_mm_kernel(
    const float* __restrict__ x, const float* __restrict__ W,
    float* __restrict__ out, int n)
{
    __shared__ float Wl[64 * 32];
    for (int i = threadIdx.x; i < 64 * 32; i += 256) Wl[i] = W[i];
    __syncthreads();
    const int idx = blockIdx.x * 256 + threadIdx.x;
    const int row = idx >> 5, c = idx & 31;
    if (row >= n) return;
    const float* xr = x + (size_t)row * 64;
    float acc = 0.f;
#pragma unroll
    for (int q = 0; q < 16; ++q) {
        const float4 xv = *(const float4*)(xr + 4 * q);
        acc = fmaf(xv.x, Wl[(4 * q + 0) * 32 + c], acc);
        acc = fmaf(xv.y, Wl[(4 * q + 1) * 32 + c], acc);
        acc = fmaf(xv.z, Wl[(4 * q + 2) * 32 + c], acc);
        acc = fmaf(xv.w, Wl[(4 * q + 3) * 32 + c], acc);
    }
    out[(size_t)row * 32 + c] = acc;
}

// ---------------------------------------------------------------------------

extern "C" void kernel_launch(void* const* d_in, const int* in_sizes, int n_in,
                              void* d_out, int out_size, void* d_ws, size_t ws_size,
                              hipStream_t stream)
{
    const float* feats   = (const float*)d_in[0];
    const float* res0_W  = (const float*)d_in[1];   // (2,2,27,32,32)
    const float* res0_bn = (const float*)d_in[2];   // (2,2,4,32)
    const float* down_bn = (const float*)d_in[3];   // (4,32)
    const float* down_W  = (const float*)d_in[4];   // (8,32,64)
    const float* res1_W  = (const float*)d_in[5];   // (2,2,27,64,64)
    const float* res1_bn = (const float*)d_in[6];   // (2,2,4,64)
    const float* up_bn   = (const float*)d_in[7];   // (4,64)
    const float* up_W    = (const float*)d_in[8];   // (8,64,32)
    const float* t0_bn1  = (const float*)d_in[9];   // (4,64)
    const float* t0_W1   = (const float*)d_in[10];  // (27,64,32)
    const float* t0_bn2  = (const float*)d_in[11];  // (4,32)
    const float* t0_W2   = (const float*)d_in[12];  // (27,32,32)
    const float* t0_Wsc  = (const float*)d_in[13];  // (64,32)
    const float* t1_W    = (const float*)d_in[14];  // (2,27,32,32)
    const float* t1_bn   = (const float*)d_in[15];  // (2,4,32)
    const int* s0i = (const int*)d_in[16];
    const int* s0o = (const int*)d_in[17];
    const int* s1i = (const int*)d_in[18];
    const int* s1o = (const int*)d_in[19];
    const int* dni = (const int*)d_in[20];
    const int* dno = (const int*)d_in[21];
    const int* n1p = (const int*)d_in[22];          // device scalar n1

    const int n0 = in_sizes[0] / 32;
    const int P0 = in_sizes[16] / 27;
    const int P1 = in_sizes[18] / 27;
    const int Pd = in_sizes[20] / 8;

    // ---- workspace layout (all chunks 16B-aligned) ----
    const size_t bufN = (size_t)n0 * 64;
    float* F1 = (float*)d_ws;
    float* F2 = F1 + bufN;
    float* F3 = F2 + bufN;
    float* F4 = F3 + bufN;
    _Float16* Ha = (_Float16*)(F4 + bufN);           // fp16 ping
    _Float16* Hb = Ha + bufN;                        // pong
    int* T0r = (int*)(Hb + bufN);                    // [n0][28]
    int* T1r = T0r + (size_t)n0 * 28;                // [n0][28]
    int* Tdr = T1r + (size_t)n0 * 28;                // [n0][8]
    int* Tur = Tdr + (size_t)n0 * 8;                 // [n0][8]
    _Float16* Wt_res0 = (_Float16*)(Tur + (size_t)n0 * 8);  // 108*1024
    _Float16* Wt_down = Wt_res0 + 108 * 1024;        // 8*2048
    _Float16* Wt_res1 = Wt_down + 8 * 2048;          // 108*4096
    _Float16* Wt_up   = Wt_res1 + (size_t)108 * 4096;// 8*2048
    _Float16* Wt_t01  = Wt_up + 8 * 2048;            // 27*2048
    _Float16* Wt_t02  = Wt_t01 + 27 * 2048;          // 27*1024
    _Float16* Wt_t1   = Wt_t02 + 27 * 1024;          // 54*1024

    // ---- gather tables (single memset over contiguous T region) ----
    hipMemsetAsync(T0r, 0xFF, (size_t)n0 * 72 * 4, stream);
    auto build = [&](const int* pin, const int* pout, int K, int P,
                     int padc, const int* padd, int KPAD, int* T) {
        hipLaunchKernelGGL(build_table_kernel, dim3((K * P + 255) / 256),
                           dim3(256), 0, stream, pin, pout, K, P, padc, padd,
                           KPAD, T);
    };
    build(s0i, s0o, 27, P0, n0, nullptr, 28, T0r);
    build(s1i, s1o, 27, P1, 0, n1p, 28, T1r);
    build(dni, dno, 8, Pd, n0, nullptr, 8, Tdr);
    build(dno, dni, 8, Pd, 0, n1p, 8, Tur);   // up: roles swapped

    // ---- merged weight convert+transpose (1 launch) ----
    WAll wa;
    wa.s[0] = {res0_W, Wt_res0, 108 * 1024, 32, 32};
    wa.s[1] = {down_W, Wt_down, 8 * 2048, 32, 64};
    wa.s[2] = {res1_W, Wt_res1, 108 * 4096, 64, 64};
    wa.s[3] = {up_W,   Wt_up,   8 * 2048, 64, 32};
    wa.s[4] = {t0_W1,  Wt_t01,  27 * 2048, 64, 32};
    wa.s[5] = {t0_W2,  Wt_t02,  27 * 1024, 32, 32};
    wa.s[6] = {t1_W,   Wt_t1,   54 * 1024, 32, 32};
    hipLaunchKernelGGL(wcvt_all_kernel, dim3((108 * 4096 + 255) / 256, 7),
                       dim3(256), 0, stream, wa);

    const int g32 = (n0 * 32 + 255) / 256;
    const int g64 = (n0 * 64 + 255) / 256;
    const int gm64 = (n0 + 63) / 64;   // BM=64 grids
    const int gm32 = (n0 + 31) / 32;   // BM=32 grids (level-1: early exit)

    // 32->32 K=27: BM=64 (WR=2,WC=2,M_REP=2), LDS ~19KB, MINW=8
    auto mc3232 = [&](const _Float16* xin, const _Float16* Wtp, const int* T,
                      const float* add, float* fo, const float* bn, _Float16* ho,
                      int nc, const int* nd) {
        hipLaunchKernelGGL((mconv_kernel<32, 32, 27, 28, 2, 2, 2, 8>),
                           dim3(gm64), dim3(256), 0, stream,
                           xin, Wtp, T, add, fo, bn, ho, nc, nd);
    };
    // 64->64 K=27: BM=32 (WR=1,WC=4,M_REP=2), LDS ~27KB, MINW=4
    auto mc6464 = [&](const _Float16* xin, const _Float16* Wtp,
                      const float* add, float* fo, const float* bn, _Float16* ho) {
        hipLaunchKernelGGL((mconv_kernel<64, 64, 27, 28, 1, 4, 2, 4>),
                           dim3(gm32), dim3(256), 0, stream,
                           xin, Wtp, T1r, add, fo, bn, ho, 0, n1p);
    };

    // 0: first bn_relu (feats -> Ha)
    hipLaunchKernelGGL((bn_relu_kernel<32>), dim3(g32), dim3(256), 0, stream,
                       feats, res0_bn + 0 * 128, Ha, n0, nullptr);
    // 1: res0.0 conv0: Ha -> Hb
    mc3232(Ha, Wt_res0 + 0 * 27 * 1024, T0r, nullptr, nullptr,
           res0_bn + 1 * 128, Hb, n0, nullptr);
    // 2: res0.0 conv1 (+feats): Hb -> F2, Ha
    mc3232(Hb, Wt_res0 + 1 * 27 * 1024, T0r, feats, F2,
           res0_bn + 2 * 128, Ha, n0, nullptr);
    // 3: res0.1 conv0: Ha -> Hb
    mc3232(Ha, Wt_res0 + 2 * 27 * 1024, T0r, nullptr, nullptr,
           res0_bn + 3 * 128, Hb, n0, nullptr);
    // 4: res0.1 conv1 (+F2): Hb -> F3 (identity), Ha [bn=down_bn]
    mc3232(Hb, Wt_res0 + 3 * 27 * 1024, T0r, F2, F3, down_bn, Ha, n0, nullptr);
    // 5: down conv (32->64, K=8, BM=32): Ha -> F1 (n1 x 64), Hb
    hipLaunchKernelGGL((mconv_kernel<32, 64, 8, 8, 1, 4, 2, 8>),
                       dim3(gm32), dim3(256), 0, stream, Ha, Wt_down, Tdr,
                       (const float*)nullptr, F1, res1_bn + 0 * 256, Hb, 0, n1p);
    // 6: res1.0 conv0: Hb -> Ha
    mc6464(Hb, Wt_res1 + 0 * 27 * 4096, nullptr, nullptr, res1_bn + 1 * 256, Ha);
    // 7: res1.0 conv1 (+F1): Ha -> F4, Hb
    mc6464(Ha, Wt_res1 + 1 * 27 * 4096, F1, F4, res1_bn + 2 * 256, Hb);
    // 8: res1.1 conv0: Hb -> Ha
    mc6464(Hb, Wt_res1 + 2 * 27 * 4096, nullptr, nullptr, res1_bn + 3 * 256, Ha);
    // 9: res1.1 conv1 (+F4): Ha -> F1, Hb [bn=up_bn]
    mc6464(Ha, Wt_res1 + 3 * 27 * 4096, F4, F1, up_bn, Hb);
    // 10: up conv (64->32, K=8, BM=32): Hb(level1) -> F2 (n0 x 32)
    hipLaunchKernelGGL((mconv_kernel<64, 32, 8, 8, 2, 2, 1, 8>),
                       dim3(gm32), dim3(256), 0, stream, Hb, Wt_up, Tur,
                       (const float*)nullptr, F2, (const float*)nullptr,
                       (_Float16*)nullptr, n0, nullptr);
    // 11: concat+bn: [F3|F2] -> F4 fp32, Ha fp16 [bn=t0_bn1]
    hipLaunchKernelGGL(concat_bn_kernel, dim3(g64), dim3(256), 0, stream,
                       F3, F2, F4, t0_bn1, Ha, n0);
    // 12: tail0 conv1 (64->32, K=27, BM=32): Ha -> Hb [bn=t0_bn2]
    hipLaunchKernelGGL((mconv_kernel<64, 32, 27, 28, 2, 2, 1, 8>),
                       dim3(gm32), dim3(256), 0, stream, Ha, Wt_t01, T0r,
                       (const float*)nullptr, (float*)nullptr, t0_bn2, Hb,
                       n0, nullptr);
    // 13: shortcut: F2 = F4 @ Wsc
    hipLaunchKernelGGL(dense_mm_kernel, dim3(g32), dim3(256), 0, stream,
                       F4, t0_Wsc, F2, n0);
    // 14: tail0 conv2 (+F2): Hb -> F2, Ha [bn=t1_bn0]  (1:1 in-place safe)
    mc3232(Hb, Wt_t02, T0r, F2, F2, t1_bn + 0 * 128, Ha, n0, nullptr);
    // 15: tail1 conv0: Ha -> Hb
    mc3232(Ha, Wt_t1 + 0 * 27 * 1024, T0r, nullptr, nullptr,
           t1_bn + 1 * 128, Hb, n0, nullptr);
    // 16: tail1 conv1 (+F2): Hb -> d_out
    mc3232(Hb, Wt_t1 + 1 * 27 * 1024, T0r, F2, (float*)d_out,
           nullptr, nullptr, n0, nullptr);
}